// Round 2
// baseline (9486.048 us; speedup 1.0000x reference)
//
#include <hip/hip_runtime.h>
#include <hip/hip_fp16.h>

#define BB 2048
#define SS 512
#define FF 32
#define HH 128
#define G3 384
#define TO 24

typedef unsigned int uint;

// ---- workspace layout (bytes) ----
#define OFF_ENCOUT 0ull                                      // half[B][S][H]
#define OFF_HFIN   (OFF_ENCOUT + (size_t)BB*SS*HH*2)         // float[B][H]
#define OFF_ATTNT  (OFF_HFIN + (size_t)BB*HH*4)              // half[160][512]
#define OFF_WIHT2  (OFF_ATTNT + (size_t)160*512*2)           // half[64][384][2] (k-pairs)
#define OFF_WHHT2  (OFF_WIHT2 + (size_t)64*384*2*2)
#define OFF_OUT1T  (OFF_WHHT2 + (size_t)64*384*2*2)          // half[128][32]

// ================= prep: transpose + fp16-pack decoder weights =================
__global__ void prep_kernel(const float* attn_W, const float* dec_Wih, const float* dec_Whh,
                            const float* out1_W,
                            __half* attnT, __half* wihT2, __half* whhT2, __half* out1T) {
  int i = blockIdx.x * 256 + threadIdx.x;
  if (i < 160*512) {                       // attnT[k][s] = attn_W[s][k]
    int k = i >> 9, s = i & 511;
    attnT[i] = __float2half(attn_W[s*160 + k]); return;
  }
  i -= 160*512;
  if (i < 128*384) {                       // wihT2 slot = k2*768 + j*2 + p ; k = 2*k2+p
    int k2 = i / 768, r = i % 768, j = r >> 1, p = r & 1;
    wihT2[i] = __float2half(dec_Wih[j*128 + (k2*2 + p)]); return;
  }
  i -= 128*384;
  if (i < 128*384) {
    int k2 = i / 768, r = i % 768, j = r >> 1, p = r & 1;
    whhT2[i] = __float2half(dec_Whh[j*128 + (k2*2 + p)]); return;
  }
  i -= 128*384;
  if (i < 128*32) {                        // out1T[k][f] = out1_W[f][k]
    int k = i >> 5, f = i & 31;
    out1T[i] = __float2half(out1_W[f*128 + k]);
  }
}

// ================= encoder: 8 batches/block, 512 steps =================
struct EncSmem {
  __half whhT[128*384];   // [k][j] fp16
  __half wihT[32*384];    // [f][j] fp16
  float  h[128*8];        // [k][b]
  float  x[32*8];         // [f][b]
  float  g[8*384];        // [b][j]  (j<256: gi+gh+biases; j>=256: gi+bih)
  float  ghn[8*128];      // [b][hj] (gh_n + bhh)
  float  bih[384];
  float  bhh[384];
};

__global__ void __launch_bounds__(192) enc_kernel(const float* __restrict__ xb,
    const float* __restrict__ Wih, const float* __restrict__ Whh,
    const float* __restrict__ bih, const float* __restrict__ bhh,
    __half* __restrict__ enc_out, float* __restrict__ hfin) {
  __shared__ EncSmem sm;
  const int tid = threadIdx.x;
  const int b0 = blockIdx.x * 8;

  for (int i = tid; i < 128*384; i += 192) { int k = i/384, j = i%384; sm.whhT[i] = __float2half(Whh[j*128 + k]); }
  for (int i = tid; i < 32*384;  i += 192) { int f = i/384, j = i%384; sm.wihT[i] = __float2half(Wih[j*32 + f]); }
  for (int i = tid; i < 384; i += 192) { sm.bih[i] = bih[i]; sm.bhh[i] = bhh[i]; }
  for (int i = tid; i < 1024; i += 192) sm.h[i] = 0.f;
  __syncthreads();

  const int bp  = tid & 3;      // batch pair id: b = 2*bp, 2*bp+1
  const int bp2 = bp * 2;
  const int jq  = tid >> 2;     // [0,48): 8 consecutive j
  const int jbase = jq * 8;

  for (int t = 0; t < 512; ++t) {
    for (int i = tid; i < 256; i += 192) {
      int b = i >> 5, f = i & 31;
      sm.x[f*8 + b] = xb[((size_t)(b0 + b)*512 + t)*32 + f];
    }
    __syncthreads();

    float acc[8][2], acch[8][2];
    #pragma unroll
    for (int jj = 0; jj < 8; ++jj) { acc[jj][0]=0.f; acc[jj][1]=0.f; acch[jj][0]=0.f; acch[jj][1]=0.f; }

    // g_i = Wih @ x
    for (int k = 0; k < 32; ++k) {
      const uint4 wraw = *(const uint4*)(sm.wihT + k*384 + jbase);
      const float2 xv  = *(const float2*)(sm.x + k*8 + bp2);
      const __half2* wh = reinterpret_cast<const __half2*>(&wraw);
      #pragma unroll
      for (int jp = 0; jp < 4; ++jp) {
        float2 wf = __half22float2(wh[jp]);
        acc[2*jp  ][0] += wf.x*xv.x; acc[2*jp  ][1] += wf.x*xv.y;
        acc[2*jp+1][0] += wf.y*xv.x; acc[2*jp+1][1] += wf.y*xv.y;
      }
    }
    // g_h = Whh @ h
    #pragma unroll 2
    for (int k = 0; k < 128; ++k) {
      const uint4 wraw = *(const uint4*)(sm.whhT + k*384 + jbase);
      const float2 hv  = *(const float2*)(sm.h + k*8 + bp2);
      const __half2* wh = reinterpret_cast<const __half2*>(&wraw);
      #pragma unroll
      for (int jp = 0; jp < 4; ++jp) {
        float2 wf = __half22float2(wh[jp]);
        acch[2*jp  ][0] += wf.x*hv.x; acch[2*jp  ][1] += wf.x*hv.y;
        acch[2*jp+1][0] += wf.y*hv.x; acch[2*jp+1][1] += wf.y*hv.y;
      }
    }

    #pragma unroll
    for (int bb = 0; bb < 2; ++bb) {
      const int b = bp2 + bb;
      float tmp[8];
      #pragma unroll
      for (int jj = 0; jj < 8; ++jj) {
        int j = jbase + jj;
        tmp[jj] = (jq < 32) ? (acc[jj][bb] + acch[jj][bb] + sm.bih[j] + sm.bhh[j])
                            : (acc[jj][bb] + sm.bih[j]);
      }
      *(float4*)(sm.g + b*384 + jbase)     = *(float4*)&tmp[0];
      *(float4*)(sm.g + b*384 + jbase + 4) = *(float4*)&tmp[4];
      if (jq >= 32) {
        float tmp2[8];
        #pragma unroll
        for (int jj = 0; jj < 8; ++jj) tmp2[jj] = acch[jj][bb] + sm.bhh[jbase + jj];
        *(float4*)(sm.ghn + b*128 + (jbase - 256))     = *(float4*)&tmp2[0];
        *(float4*)(sm.ghn + b*128 + (jbase - 256) + 4) = *(float4*)&tmp2[4];
      }
    }
    __syncthreads();

    for (int i = tid; i < 1024; i += 192) {
      int b = i >> 7, hj = i & 127;
      float gr   = sm.g[b*384 + hj];
      float gz   = sm.g[b*384 + 128 + hj];
      float gin  = sm.g[b*384 + 256 + hj];
      float ghnv = sm.ghn[b*128 + hj];
      float r = 1.f / (1.f + __expf(-gr));
      float z = 1.f / (1.f + __expf(-gz));
      float narg = gin + r * ghnv;
      float n = 1.f - 2.f / (__expf(2.f*narg) + 1.f);
      float hnew = (1.f - z)*n + z*sm.h[hj*8 + b];
      sm.h[hj*8 + b] = hnew;
      enc_out[((size_t)(b0 + b)*512 + t)*128 + hj] = __float2half(hnew);
    }
    __syncthreads();
  }
  for (int i = tid; i < 1024; i += 192) {
    int b = i >> 7, hj = i & 127;
    hfin[(b0 + b)*128 + hj] = sm.h[hj*8 + b];
  }
}

// ================= decoder: 1 batch/block, enc_out resident in LDS =================
struct DecSmem {
  __half E[512*128];      // enc_out[b] fp16
  float w[512];
  float red[256];
  float ctxp[8*128];
  float ctx[128];
  float h[128];
  float y[32];
  float gi[384];
  float gh[384];
  float outp[8*32];
  float attn_b[512];
  float dbih[384];
  float dbhh[384];
  float o1b[32];
  float o2w[32];
  float o2b;
};

__global__ void __launch_bounds__(256) dec_kernel(const float* __restrict__ xb,
    const __half* __restrict__ enc_out, const float* __restrict__ hfin,
    const __half* __restrict__ attnT, const float* __restrict__ attn_b,
    const __half* __restrict__ wihT2, const __half* __restrict__ whhT2,
    const float* __restrict__ dbih, const float* __restrict__ dbhh,
    const __half* __restrict__ out1T, const float* __restrict__ out1_b,
    const float* __restrict__ out2_W, const float* __restrict__ out2_b,
    float* __restrict__ out) {
  __shared__ DecSmem sm;
  const int tid = threadIdx.x;
  const int b = blockIdx.x;

  { const uint* src = (const uint*)(enc_out + (size_t)b*512*128);
    uint* dst = (uint*)sm.E;
    for (int i = tid; i < 32768; i += 256) dst[i] = src[i]; }
  if (tid < 128) sm.h[tid] = hfin[b*128 + tid];
  if (tid < 32)  sm.y[tid] = xb[((size_t)b*512 + 511)*32 + tid];
  for (int i = tid; i < 512; i += 256) sm.attn_b[i] = attn_b[i];
  for (int i = tid; i < 384; i += 256) { sm.dbih[i] = dbih[i]; sm.dbhh[i] = dbhh[i]; }
  if (tid < 32)  { sm.o1b[tid] = out1_b[tid]; sm.o2w[tid] = out2_W[tid]; }
  if (tid == 0)  sm.o2b = out2_b[0];
  __syncthreads();

  const uint* attnT_u = (const uint*)attnT;   // [k][256] half2
  const uint* wih_u   = (const uint*)wihT2;   // [k2][384] half2 (k-pairs)
  const uint* whh_u   = (const uint*)whhT2;

  for (int tt = 0; tt < TO; ++tt) {
    // ---- attention logits, s = 2*tid, 2*tid+1 ----
    float l0 = sm.attn_b[2*tid], l1 = sm.attn_b[2*tid + 1];
    for (int k = 0; k < 160; ++k) {
      float a = (k < 128) ? sm.h[k] : sm.y[k - 128];
      uint wv = attnT_u[k*256 + tid];
      float2 wf = __half22float2(*reinterpret_cast<__half2*>(&wv));
      l0 += a * wf.x; l1 += a * wf.y;
    }
    // ---- softmax ----
    sm.red[tid] = fmaxf(l0, l1); __syncthreads();
    for (int s2 = 128; s2 > 0; s2 >>= 1) { if (tid < s2) sm.red[tid] = fmaxf(sm.red[tid], sm.red[tid + s2]); __syncthreads(); }
    float M = sm.red[0];
    __syncthreads();
    float e0 = __expf(l0 - M), e1 = __expf(l1 - M);
    sm.w[2*tid] = e0; sm.w[2*tid + 1] = e1;
    sm.red[tid] = e0 + e1; __syncthreads();
    for (int s2 = 128; s2 > 0; s2 >>= 1) { if (tid < s2) sm.red[tid] += sm.red[tid + s2]; __syncthreads(); }
    float inv = 1.f / sm.red[0];
    __syncthreads();

    // ---- ctx = (sum_s w[s] * E[s]) * inv ----
    { const int hq = tid & 31, sg = tid >> 5;
      float c0=0.f, c1=0.f, c2=0.f, c3=0.f;
      for (int s = sg*64; s < sg*64 + 64; ++s) {
        float wsv = sm.w[s];
        uint2 ev = *(const uint2*)(sm.E + s*128 + hq*4);
        float2 f01 = __half22float2(*reinterpret_cast<__half2*>(&ev.x));
        float2 f23 = __half22float2(*reinterpret_cast<__half2*>(&ev.y));
        c0 += wsv*f01.x; c1 += wsv*f01.y; c2 += wsv*f23.x; c3 += wsv*f23.y;
      }
      sm.ctxp[sg*128 + hq*4 + 0] = c0; sm.ctxp[sg*128 + hq*4 + 1] = c1;
      sm.ctxp[sg*128 + hq*4 + 2] = c2; sm.ctxp[sg*128 + hq*4 + 3] = c3; }
    __syncthreads();
    if (tid < 128) {
      float c = 0.f;
      #pragma unroll
      for (int g = 0; g < 8; ++g) c += sm.ctxp[g*128 + tid];
      sm.ctx[tid] = c * inv;
    }
    __syncthreads();

    // ---- xp = dec_Wih@ctx + bih ; gh = dec_Whh@h + bhh ----
    for (int j = tid; j < 384; j += 256) {
      float ai = 0.f, ah = 0.f;
      for (int k2 = 0; k2 < 64; ++k2) {
        float2 cv = *(const float2*)(sm.ctx + 2*k2);
        float2 hv = *(const float2*)(sm.h + 2*k2);
        uint wv = wih_u[k2*384 + j];
        float2 wf = __half22float2(*reinterpret_cast<__half2*>(&wv));
        ai += wf.x*cv.x + wf.y*cv.y;
        uint wv2 = whh_u[k2*384 + j];
        float2 wf2 = __half22float2(*reinterpret_cast<__half2*>(&wv2));
        ah += wf2.x*hv.x + wf2.y*hv.y;
      }
      sm.gi[j] = ai + sm.dbih[j];
      sm.gh[j] = ah + sm.dbhh[j];
    }
    __syncthreads();
    // ---- GRU gates ----
    if (tid < 128) {
      float r = 1.f / (1.f + __expf(-(sm.gi[tid] + sm.gh[tid])));
      float z = 1.f / (1.f + __expf(-(sm.gi[tid+128] + sm.gh[tid+128])));
      float narg = sm.gi[tid+256] + r * sm.gh[tid+256];
      float n = 1.f - 2.f / (__expf(2.f*narg) + 1.f);
      sm.h[tid] = (1.f - z)*n + z*sm.h[tid];
    }
    __syncthreads();
    // ---- out1 = h@out1_W.T + b (raw -> y) ----
    { const int f = tid & 31, kq = tid >> 5;
      float acc = 0.f;
      for (int k = kq*16; k < kq*16 + 16; ++k) acc += __half2float(out1T[k*32 + f]) * sm.h[k];
      sm.outp[kq*32 + f] = acc; }
    __syncthreads();
    if (tid < 32) {
      float o = sm.o1b[tid];
      #pragma unroll
      for (int g = 0; g < 8; ++g) o += sm.outp[g*32 + tid];
      sm.y[tid] = o;                                  // raw out feeds next attention
      sm.outp[tid] = fmaxf(o, 0.f) * sm.o2w[tid];     // relu(out) * out2_W
    }
    __syncthreads();
    if (tid == 0) {
      float o = sm.o2b;
      for (int f = 0; f < 32; ++f) o += sm.outp[f];
      out[(size_t)b*TO + tt] = fmaxf(o, 0.f);
    }
    __syncthreads();
  }
}

extern "C" void kernel_launch(void* const* d_in, const int* in_sizes, int n_in,
                              void* d_out, int out_size, void* d_ws, size_t ws_size,
                              hipStream_t stream) {
  const float* xb      = (const float*)d_in[0];
  const float* enc_Wih = (const float*)d_in[1];
  const float* enc_Whh = (const float*)d_in[2];
  const float* enc_bih = (const float*)d_in[3];
  const float* enc_bhh = (const float*)d_in[4];
  const float* attn_W  = (const float*)d_in[5];
  const float* attn_b  = (const float*)d_in[6];
  const float* dec_Wih = (const float*)d_in[7];
  const float* dec_Whh = (const float*)d_in[8];
  const float* dec_bih = (const float*)d_in[9];
  const float* dec_bhh = (const float*)d_in[10];
  const float* out1_W  = (const float*)d_in[11];
  const float* out1_b  = (const float*)d_in[12];
  const float* out2_W  = (const float*)d_in[13];
  const float* out2_b  = (const float*)d_in[14];

  char* ws = (char*)d_ws;
  __half* enc_out = (__half*)(ws + OFF_ENCOUT);
  float*  hfin    = (float*)(ws + OFF_HFIN);
  __half* attnT   = (__half*)(ws + OFF_ATTNT);
  __half* wihT2   = (__half*)(ws + OFF_WIHT2);
  __half* whhT2   = (__half*)(ws + OFF_WHHT2);
  __half* out1T   = (__half*)(ws + OFF_OUT1T);

  prep_kernel<<<720, 256, 0, stream>>>(attn_W, dec_Wih, dec_Whh, out1_W, attnT, wihT2, whhT2, out1T);
  enc_kernel<<<256, 192, 0, stream>>>(xb, enc_Wih, enc_Whh, enc_bih, enc_bhh, enc_out, hfin);
  dec_kernel<<<2048, 256, 0, stream>>>(xb, enc_out, hfin, attnT, attn_b, wihT2, whhT2,
                                       dec_bih, dec_bhh, out1T, out1_b, out2_W, out2_b,
                                       (float*)d_out);
}

// Round 3
// 3605.474 us; speedup vs baseline: 2.6310x; 2.6310x over previous
//
#include <hip/hip_runtime.h>
#include <hip/hip_fp16.h>

#define BB 2048
#define SS 512
#define FF 32
#define HH 128
#define G3 384
#define TO 24

typedef unsigned int uint;

using half8 = __attribute__((ext_vector_type(8))) _Float16;
using f32x4 = __attribute__((ext_vector_type(4))) float;

// ---- workspace layout (bytes) ----
#define OFF_ENCOUT 0ull                                      // half[B][S][H]
#define OFF_HFIN   (OFF_ENCOUT + (size_t)BB*SS*HH*2)         // float[B][H]
#define OFF_ATTNT  (OFF_HFIN + (size_t)BB*HH*4)              // half[160][512]
#define OFF_WIHT2  (OFF_ATTNT + (size_t)160*512*2)           // half[64][384][2] (k-pairs)
#define OFF_WHHT2  (OFF_WIHT2 + (size_t)64*384*2*2)
#define OFF_OUT1T  (OFF_WHHT2 + (size_t)64*384*2*2)          // half[128][32]
#define OFF_WF     (OFF_OUT1T + (size_t)128*32*2)            // half[61440] enc B-frags

// ================= prep: transpose + fp16-pack weights =================
__global__ void prep_kernel(const float* attn_W, const float* dec_Wih, const float* dec_Whh,
                            const float* out1_W, const float* enc_Wih, const float* enc_Whh,
                            __half* attnT, __half* wihT2, __half* whhT2, __half* out1T,
                            __half* Wf) {
  int i = blockIdx.x * 256 + threadIdx.x;
  if (i < 160*512) {                       // attnT[k][s] = attn_W[s][k]
    int k = i >> 9, s = i & 511;
    attnT[i] = __float2half(attn_W[s*160 + k]); return;
  }
  i -= 160*512;
  if (i < 128*384) {                       // wihT2 slot = k2*768 + j*2 + p ; k = 2*k2+p
    int k2 = i / 768, r = i % 768, j = r >> 1, p = r & 1;
    wihT2[i] = __float2half(dec_Wih[j*128 + (k2*2 + p)]); return;
  }
  i -= 128*384;
  if (i < 128*384) {
    int k2 = i / 768, r = i % 768, j = r >> 1, p = r & 1;
    whhT2[i] = __float2half(dec_Whh[j*128 + (k2*2 + p)]); return;
  }
  i -= 128*384;
  if (i < 128*32) {                        // out1T[k][f] = out1_W[f][k]
    int k = i >> 5, f = i & 31;
    out1T[i] = __float2half(out1_W[f*128 + k]); return;
  }
  i -= 128*32;
  if (i < 61440) {
    // enc B fragments: idx = (((w*6+tt)*5+kb)*64 + lane)*8 + e
    // frag elem: B[k][J], k = kb*32 + (lane>>4)*8 + e, J = g*128 + w*32 + sub*16 + (lane&15)
    int e = i & 7, l = (i >> 3) & 63;
    int q = i >> 9;
    int kb = q % 5, tt = (q / 5) % 6, w = q / 30;
    int g = tt >> 1, sub = tt & 1;
    int k = kb*32 + ((l >> 4) << 3) + e;
    int J = g*128 + w*32 + sub*16 + (l & 15);
    float v = (k < 128) ? enc_Whh[J*128 + k] : enc_Wih[J*32 + (k - 128)];
    Wf[i] = __float2half(v);
  }
}

// ================= encoder: MFMA, 16 batches/block, 512 steps =================
#define HXS 168   // halves per LDS row (336B: 2-way-max bank aliasing, 16B aligned)

__global__ void __launch_bounds__(256, 1) enc_kernel(
    const float* __restrict__ xb, const __half* __restrict__ Wf,
    const float* __restrict__ bih, const float* __restrict__ bhh,
    __half* __restrict__ enc_out, float* __restrict__ hfin) {
  __shared__ __align__(16) _Float16 hx[16][HXS];   // [m][k] : k<128 h(fp16), 128..159 x(fp16)
  const int tid  = threadIdx.x;
  const int lane = tid & 63, w = tid >> 6;
  const int l15  = lane & 15, lq = lane >> 4;
  const int b0   = blockIdx.x * 16;

  // --- B fragments: 6 tiles (r0,r1,z0,z1,n0,n1) x 5 k-blocks, resident in VGPRs ---
  half8 Bf[6][5];
  { const half8* wfp = (const half8*)Wf;
    #pragma unroll
    for (int tt = 0; tt < 6; ++tt)
      #pragma unroll
      for (int kb = 0; kb < 5; ++kb)
        Bf[tt][kb] = wfp[((w*6 + tt)*5 + kb)*64 + lane];
  }

  // --- per-lane biases (col-dependent only) ---
  float br[2], bz[2], bnh[2], bni[2];
  #pragma unroll
  for (int sub = 0; sub < 2; ++sub) {
    int j = w*32 + sub*16 + l15;
    br[sub]  = bih[j]       + bhh[j];
    bz[sub]  = bih[128 + j] + bhh[128 + j];
    bnh[sub] = bhh[256 + j];
    bni[sub] = bih[256 + j];
  }
  float hreg[2][4] = {{0.f,0.f,0.f,0.f},{0.f,0.f,0.f,0.f}};

  const int m = tid >> 4, c = tid & 15;   // staging roles: 16 rows x 16 cols

  // init: zero h-part, load x_0
  { half8 zz = {};
    *(half8*)&hx[m][c*8] = zz; }
  { float2 x0 = *(const float2*)&xb[((size_t)(b0 + m)*512 + 0)*32 + c*2];
    *(__half2*)&hx[m][128 + c*2] = __floats2half2_rn(x0.x, x0.y); }
  __syncthreads();

  for (int t = 0; t < 512; ++t) {
    // prefetch x_{t+1} into registers (latency hidden under MFMA+gates)
    const int tn = (t < 511) ? t + 1 : 511;
    float2 xpre = *(const float2*)&xb[((size_t)(b0 + m)*512 + tn)*32 + c*2];

    // A fragments: [h | x] row l15, 8 contiguous k per lane
    half8 A[5];
    #pragma unroll
    for (int kb = 0; kb < 5; ++kb)
      A[kb] = *(const half8*)&hx[l15][kb*32 + lq*8];

    f32x4 Cr[2], Cz[2], Cnh[2], Cni[2];
    #pragma unroll
    for (int sub = 0; sub < 2; ++sub) {
      Cr[sub] = (f32x4){0.f,0.f,0.f,0.f};
      Cz[sub] = (f32x4){0.f,0.f,0.f,0.f};
      Cnh[sub] = (f32x4){0.f,0.f,0.f,0.f};
      Cni[sub] = (f32x4){0.f,0.f,0.f,0.f};
    }
    #pragma unroll
    for (int sub = 0; sub < 2; ++sub) {
      #pragma unroll
      for (int kb = 0; kb < 5; ++kb) {
        Cr[sub] = __builtin_amdgcn_mfma_f32_16x16x32_f16(A[kb], Bf[sub][kb],     Cr[sub], 0, 0, 0);
        Cz[sub] = __builtin_amdgcn_mfma_f32_16x16x32_f16(A[kb], Bf[2 + sub][kb], Cz[sub], 0, 0, 0);
      }
      #pragma unroll
      for (int kb = 0; kb < 4; ++kb)   // n-gate: h-part (k<128) separate from x-part
        Cnh[sub] = __builtin_amdgcn_mfma_f32_16x16x32_f16(A[kb], Bf[4 + sub][kb], Cnh[sub], 0, 0, 0);
      Cni[sub] = __builtin_amdgcn_mfma_f32_16x16x32_f16(A[4], Bf[4 + sub][4], Cni[sub], 0, 0, 0);
    }
    __syncthreads();   // all hx reads done before rewrite

    // --- gates: per lane 8 h-positions (2 col-tiles x 4 rows), all register-local ---
    #pragma unroll
    for (int sub = 0; sub < 2; ++sub)
      #pragma unroll
      for (int i = 0; i < 4; ++i) {
        float r = 1.f / (1.f + __expf(-(Cr[sub][i] + br[sub])));
        float z = 1.f / (1.f + __expf(-(Cz[sub][i] + bz[sub])));
        float narg = (Cni[sub][i] + bni[sub]) + r * (Cnh[sub][i] + bnh[sub]);
        float n = 1.f - 2.f / (__expf(2.f*narg) + 1.f);
        float hnew = (1.f - z)*n + z*hreg[sub][i];
        hreg[sub][i] = hnew;
        hx[4*lq + i][w*32 + sub*16 + l15] = (_Float16)hnew;
      }
    // write x_{t+1} into hx x-slot
    *(__half2*)&hx[m][128 + c*2] = __floats2half2_rn(xpre.x, xpre.y);
    __syncthreads();   // hx updated & visible

    // enc_out coalesced copy (reads stable hx until next step's write phase)
    { half8 hv = *(const half8*)&hx[m][c*8];
      *(half8*)((void*)&enc_out[((size_t)(b0 + m)*512 + t)*128 + c*8]) = hv; }
  }

  // final hidden (exact fp32 from registers)
  #pragma unroll
  for (int sub = 0; sub < 2; ++sub)
    #pragma unroll
    for (int i = 0; i < 4; ++i)
      hfin[(size_t)(b0 + 4*lq + i)*128 + w*32 + sub*16 + l15] = hreg[sub][i];
}

// ================= decoder: 1 batch/block, enc_out resident in LDS =================
struct DecSmem {
  __half E[512*128];      // enc_out[b] fp16
  float w[512];
  float red[256];
  float ctxp[8*128];
  float ctx[128];
  float h[128];
  float y[32];
  float gi[384];
  float gh[384];
  float outp[8*32];
  float attn_b[512];
  float dbih[384];
  float dbhh[384];
  float o1b[32];
  float o2w[32];
  float o2b;
};

__global__ void __launch_bounds__(256) dec_kernel(const float* __restrict__ xb,
    const __half* __restrict__ enc_out, const float* __restrict__ hfin,
    const __half* __restrict__ attnT, const float* __restrict__ attn_b,
    const __half* __restrict__ wihT2, const __half* __restrict__ whhT2,
    const float* __restrict__ dbih, const float* __restrict__ dbhh,
    const __half* __restrict__ out1T, const float* __restrict__ out1_b,
    const float* __restrict__ out2_W, const float* __restrict__ out2_b,
    float* __restrict__ out) {
  __shared__ DecSmem sm;
  const int tid = threadIdx.x;
  const int b = blockIdx.x;

  { const uint* src = (const uint*)(enc_out + (size_t)b*512*128);
    uint* dst = (uint*)sm.E;
    for (int i = tid; i < 32768; i += 256) dst[i] = src[i]; }
  if (tid < 128) sm.h[tid] = hfin[b*128 + tid];
  if (tid < 32)  sm.y[tid] = xb[((size_t)b*512 + 511)*32 + tid];
  for (int i = tid; i < 512; i += 256) sm.attn_b[i] = attn_b[i];
  for (int i = tid; i < 384; i += 256) { sm.dbih[i] = dbih[i]; sm.dbhh[i] = dbhh[i]; }
  if (tid < 32)  { sm.o1b[tid] = out1_b[tid]; sm.o2w[tid] = out2_W[tid]; }
  if (tid == 0)  sm.o2b = out2_b[0];
  __syncthreads();

  const uint* attnT_u = (const uint*)attnT;   // [k][256] half2
  const uint* wih_u   = (const uint*)wihT2;   // [k2][384] half2 (k-pairs)
  const uint* whh_u   = (const uint*)whhT2;

  for (int tt = 0; tt < TO; ++tt) {
    // ---- attention logits, s = 2*tid, 2*tid+1 ----
    float l0 = sm.attn_b[2*tid], l1 = sm.attn_b[2*tid + 1];
    for (int k = 0; k < 160; ++k) {
      float a = (k < 128) ? sm.h[k] : sm.y[k - 128];
      uint wv = attnT_u[k*256 + tid];
      float2 wf = __half22float2(*reinterpret_cast<__half2*>(&wv));
      l0 += a * wf.x; l1 += a * wf.y;
    }
    // ---- softmax ----
    sm.red[tid] = fmaxf(l0, l1); __syncthreads();
    for (int s2 = 128; s2 > 0; s2 >>= 1) { if (tid < s2) sm.red[tid] = fmaxf(sm.red[tid], sm.red[tid + s2]); __syncthreads(); }
    float M = sm.red[0];
    __syncthreads();
    float e0 = __expf(l0 - M), e1 = __expf(l1 - M);
    sm.w[2*tid] = e0; sm.w[2*tid + 1] = e1;
    sm.red[tid] = e0 + e1; __syncthreads();
    for (int s2 = 128; s2 > 0; s2 >>= 1) { if (tid < s2) sm.red[tid] += sm.red[tid + s2]; __syncthreads(); }
    float inv = 1.f / sm.red[0];
    __syncthreads();

    // ---- ctx = (sum_s w[s] * E[s]) * inv ----
    { const int hq = tid & 31, sg = tid >> 5;
      float c0=0.f, c1=0.f, c2=0.f, c3=0.f;
      for (int s = sg*64; s < sg*64 + 64; ++s) {
        float wsv = sm.w[s];
        uint2 ev = *(const uint2*)(sm.E + s*128 + hq*4);
        float2 f01 = __half22float2(*reinterpret_cast<__half2*>(&ev.x));
        float2 f23 = __half22float2(*reinterpret_cast<__half2*>(&ev.y));
        c0 += wsv*f01.x; c1 += wsv*f01.y; c2 += wsv*f23.x; c3 += wsv*f23.y;
      }
      sm.ctxp[sg*128 + hq*4 + 0] = c0; sm.ctxp[sg*128 + hq*4 + 1] = c1;
      sm.ctxp[sg*128 + hq*4 + 2] = c2; sm.ctxp[sg*128 + hq*4 + 3] = c3; }
    __syncthreads();
    if (tid < 128) {
      float c = 0.f;
      #pragma unroll
      for (int g = 0; g < 8; ++g) c += sm.ctxp[g*128 + tid];
      sm.ctx[tid] = c * inv;
    }
    __syncthreads();

    // ---- xp = dec_Wih@ctx + bih ; gh = dec_Whh@h + bhh ----
    for (int j = tid; j < 384; j += 256) {
      float ai = 0.f, ah = 0.f;
      for (int k2 = 0; k2 < 64; ++k2) {
        float2 cv = *(const float2*)(sm.ctx + 2*k2);
        float2 hv = *(const float2*)(sm.h + 2*k2);
        uint wv = wih_u[k2*384 + j];
        float2 wf = __half22float2(*reinterpret_cast<__half2*>(&wv));
        ai += wf.x*cv.x + wf.y*cv.y;
        uint wv2 = whh_u[k2*384 + j];
        float2 wf2 = __half22float2(*reinterpret_cast<__half2*>(&wv2));
        ah += wf2.x*hv.x + wf2.y*hv.y;
      }
      sm.gi[j] = ai + sm.dbih[j];
      sm.gh[j] = ah + sm.dbhh[j];
    }
    __syncthreads();
    // ---- GRU gates ----
    if (tid < 128) {
      float r = 1.f / (1.f + __expf(-(sm.gi[tid] + sm.gh[tid])));
      float z = 1.f / (1.f + __expf(-(sm.gi[tid+128] + sm.gh[tid+128])));
      float narg = sm.gi[tid+256] + r * sm.gh[tid+256];
      float n = 1.f - 2.f / (__expf(2.f*narg) + 1.f);
      sm.h[tid] = (1.f - z)*n + z*sm.h[tid];
    }
    __syncthreads();
    // ---- out1 = h@out1_W.T + b (raw -> y) ----
    { const int f = tid & 31, kq = tid >> 5;
      float acc = 0.f;
      for (int k = kq*16; k < kq*16 + 16; ++k) acc += __half2float(out1T[k*32 + f]) * sm.h[k];
      sm.outp[kq*32 + f] = acc; }
    __syncthreads();
    if (tid < 32) {
      float o = sm.o1b[tid];
      #pragma unroll
      for (int g = 0; g < 8; ++g) o += sm.outp[g*32 + tid];
      sm.y[tid] = o;                                  // raw out feeds next attention
      sm.outp[tid] = fmaxf(o, 0.f) * sm.o2w[tid];     // relu(out) * out2_W
    }
    __syncthreads();
    if (tid == 0) {
      float o = sm.o2b;
      for (int f = 0; f < 32; ++f) o += sm.outp[f];
      out[(size_t)b*TO + tt] = fmaxf(o, 0.f);
    }
    __syncthreads();
  }
}

extern "C" void kernel_launch(void* const* d_in, const int* in_sizes, int n_in,
                              void* d_out, int out_size, void* d_ws, size_t ws_size,
                              hipStream_t stream) {
  const float* xb      = (const float*)d_in[0];
  const float* enc_Wih = (const float*)d_in[1];
  const float* enc_Whh = (const float*)d_in[2];
  const float* enc_bih = (const float*)d_in[3];
  const float* enc_bhh = (const float*)d_in[4];
  const float* attn_W  = (const float*)d_in[5];
  const float* attn_b  = (const float*)d_in[6];
  const float* dec_Wih = (const float*)d_in[7];
  const float* dec_Whh = (const float*)d_in[8];
  const float* dec_bih = (const float*)d_in[9];
  const float* dec_bhh = (const float*)d_in[10];
  const float* out1_W  = (const float*)d_in[11];
  const float* out1_b  = (const float*)d_in[12];
  const float* out2_W  = (const float*)d_in[13];
  const float* out2_b  = (const float*)d_in[14];

  char* ws = (char*)d_ws;
  __half* enc_out = (__half*)(ws + OFF_ENCOUT);
  float*  hfin    = (float*)(ws + OFF_HFIN);
  __half* attnT   = (__half*)(ws + OFF_ATTNT);
  __half* wihT2   = (__half*)(ws + OFF_WIHT2);
  __half* whhT2   = (__half*)(ws + OFF_WHHT2);
  __half* out1T   = (__half*)(ws + OFF_OUT1T);
  __half* Wf      = (__half*)(ws + OFF_WF);

  prep_kernel<<<960, 256, 0, stream>>>(attn_W, dec_Wih, dec_Whh, out1_W, enc_Wih, enc_Whh,
                                       attnT, wihT2, whhT2, out1T, Wf);
  enc_kernel<<<128, 256, 0, stream>>>(xb, Wf, enc_bih, enc_bhh, enc_out, hfin);
  dec_kernel<<<2048, 256, 0, stream>>>(xb, enc_out, hfin, attnT, attn_b, wihT2, whhT2,
                                       dec_bih, dec_bhh, out1T, out1_b, out2_W, out2_b,
                                       (float*)d_out);
}

// Round 4
// 1966.162 us; speedup vs baseline: 4.8247x; 1.8338x over previous
//
#include <hip/hip_runtime.h>
#include <hip/hip_fp16.h>

#define BB 2048
#define SS 512
#define FF 32
#define HH 128
#define TO 24

typedef unsigned int uint;
using half4 = __attribute__((ext_vector_type(4))) _Float16;
using half8 = __attribute__((ext_vector_type(8))) _Float16;
using f32x4 = __attribute__((ext_vector_type(4))) float;

// ---- workspace layout (bytes) ----
#define OFF_ENCOUT 0ull                                      // half[B][S][H]
#define OFF_HFIN  (OFF_ENCOUT + (size_t)BB*SS*HH*2)          // float[B][H]
#define OFF_ATTNF (OFF_HFIN + (size_t)BB*HH*4)               // half[81920]  logits B-frags
#define OFF_DECF  (OFF_ATTNF + (size_t)81920*2)              // half[98304]  GRU B-frags
#define OFF_OUT1T (OFF_DECF + (size_t)98304*2)               // half[128*32]
#define OFF_WF    (OFF_OUT1T + (size_t)4096*2)               // half[61440]  enc B-frags

// ================= prep: pack weights into MFMA fragment order =================
__global__ void prep_kernel(const float* attn_W, const float* dec_Wih, const float* dec_Whh,
                            const float* out1_W, const float* enc_Wih, const float* enc_Whh,
                            __half* attnF, __half* decF, __half* out1T, __half* Wf) {
  int i = blockIdx.x * 256 + threadIdx.x;
  if (i < 81920) {
    // attnF: frag idx = ((w*8+st)*5+kb)*512 + l*8 + e ; B[k][s]=attn_W[s][k]
    int e = i & 7, l = (i >> 3) & 63, kb = (i >> 9) % 5, st = (i / 2560) & 7, w = i / 20480;
    int k = kb*32 + ((l >> 4) << 3) + e;
    int s = w*128 + st*16 + (l & 15);
    attnF[i] = __float2half(attn_W[s*160 + k]);
    return;
  }
  i -= 81920;
  if (i < 98304) {
    // decF: frag idx = (w*48+fi)*512 + l*8 + e
    int e = i & 7, l = (i >> 3) & 63, fi = (i >> 9) % 48, w = i / 24576;
    int lq = l >> 4, l15 = l & 15;
    float val;
    if (fi < 32) {            // r/z combined [ctx|h] K=256
      int g2 = fi >> 4, sub = (fi >> 3) & 1, kb = fi & 7;
      int k = kb*32 + lq*8 + e, j = w*32 + sub*16 + l15, jg = g2*128 + j;
      val = (k < 128) ? dec_Wih[jg*128 + k] : dec_Whh[jg*128 + (k - 128)];
    } else {                  // nh (Whh) then ni (Wih), K=128 each
      int f2 = fi - 32, cat = f2 >> 3, sub = (f2 >> 2) & 1, kb4 = f2 & 3;
      int k = kb4*32 + lq*8 + e, j = 256 + w*32 + sub*16 + l15;
      val = cat ? dec_Wih[j*128 + k] : dec_Whh[j*128 + k];
    }
    decF[i] = __float2half(val);
    return;
  }
  i -= 98304;
  if (i < 4096) {             // out1T[k][f] = out1_W[f][k]
    int k = i >> 5, f = i & 31;
    out1T[i] = __float2half(out1_W[f*128 + k]);
    return;
  }
  i -= 4096;
  if (i < 61440) {            // enc B-frags (unchanged layout)
    int e = i & 7, l = (i >> 3) & 63, q = i >> 9;
    int kb = q % 5, tt = (q / 5) % 6, w = q / 30;
    int g = tt >> 1, sub = tt & 1;
    int k = kb*32 + ((l >> 4) << 3) + e;
    int J = g*128 + w*32 + sub*16 + (l & 15);
    float v = (k < 128) ? enc_Whh[J*128 + k] : enc_Wih[J*32 + (k - 128)];
    Wf[i] = __float2half(v);
  }
}

// ================= encoder: MFMA, 8 batches/block, 256 blocks =================
#define HXS 168

__global__ void __launch_bounds__(256, 1) enc_kernel(
    const float* __restrict__ xb, const __half* __restrict__ Wf,
    const float* __restrict__ bih, const float* __restrict__ bhh,
    __half* __restrict__ enc_out, float* __restrict__ hfin) {
  __shared__ __align__(16) _Float16 hx[16][HXS];   // rows 0..7 live, 8..15 zero
  const int tid  = threadIdx.x;
  const int lane = tid & 63, wid = tid >> 6;
  const int l15  = lane & 15, lq = lane >> 4;
  const int b0   = blockIdx.x * 8;

  half8 Bf[6][5];
  { const half8* wfp = (const half8*)Wf;
    #pragma unroll
    for (int tt = 0; tt < 6; ++tt)
      #pragma unroll
      for (int kb = 0; kb < 5; ++kb)
        Bf[tt][kb] = wfp[((wid*6 + tt)*5 + kb)*64 + lane];
  }

  float br[2], bz[2], bnh[2], bni[2];
  #pragma unroll
  for (int sub = 0; sub < 2; ++sub) {
    int j = wid*32 + sub*16 + l15;
    br[sub]  = bih[j]       + bhh[j];
    bz[sub]  = bih[128 + j] + bhh[128 + j];
    bnh[sub] = bhh[256 + j];
    bni[sub] = bih[256 + j];
  }
  float hreg[2][4] = {{0.f,0.f,0.f,0.f},{0.f,0.f,0.f,0.f}};

  const int m2 = tid >> 5, c2 = tid & 31;   // staging: 8 rows x 32 cols

  for (int i = tid; i < 16*HXS; i += 256) (&hx[0][0])[i] = (_Float16)0.f;
  __syncthreads();
  hx[m2][128 + c2] = (_Float16)xb[((size_t)(b0 + m2)*512 + 0)*32 + c2];
  __syncthreads();

  for (int t = 0; t < 512; ++t) {
    const int tn = (t < 511) ? t + 1 : 511;
    float xpre = xb[((size_t)(b0 + m2)*512 + tn)*32 + c2];

    half8 A[5];
    #pragma unroll
    for (int kb = 0; kb < 5; ++kb)
      A[kb] = *(const half8*)&hx[l15][kb*32 + lq*8];

    f32x4 Cr[2], Cz[2], Cnh[2], Cni[2];
    #pragma unroll
    for (int sub = 0; sub < 2; ++sub) {
      Cr[sub] = (f32x4){0.f,0.f,0.f,0.f};
      Cz[sub] = (f32x4){0.f,0.f,0.f,0.f};
      Cnh[sub] = (f32x4){0.f,0.f,0.f,0.f};
      Cni[sub] = (f32x4){0.f,0.f,0.f,0.f};
    }
    #pragma unroll
    for (int sub = 0; sub < 2; ++sub) {
      #pragma unroll
      for (int kb = 0; kb < 5; ++kb) {
        Cr[sub] = __builtin_amdgcn_mfma_f32_16x16x32_f16(A[kb], Bf[sub][kb],     Cr[sub], 0, 0, 0);
        Cz[sub] = __builtin_amdgcn_mfma_f32_16x16x32_f16(A[kb], Bf[2 + sub][kb], Cz[sub], 0, 0, 0);
      }
      #pragma unroll
      for (int kb = 0; kb < 4; ++kb)
        Cnh[sub] = __builtin_amdgcn_mfma_f32_16x16x32_f16(A[kb], Bf[4 + sub][kb], Cnh[sub], 0, 0, 0);
      Cni[sub] = __builtin_amdgcn_mfma_f32_16x16x32_f16(A[4], Bf[4 + sub][4], Cni[sub], 0, 0, 0);
    }
    __syncthreads();   // all hx reads done

    #pragma unroll
    for (int sub = 0; sub < 2; ++sub)
      #pragma unroll
      for (int i = 0; i < 4; ++i) {
        float r = 1.f / (1.f + __expf(-(Cr[sub][i] + br[sub])));
        float z = 1.f / (1.f + __expf(-(Cz[sub][i] + bz[sub])));
        float narg = (Cni[sub][i] + bni[sub]) + r * (Cnh[sub][i] + bnh[sub]);
        float n = 1.f - 2.f / (__expf(2.f*narg) + 1.f);
        float hnew = (1.f - z)*n + z*hreg[sub][i];
        hreg[sub][i] = hnew;
        if (lq < 2)
          hx[4*lq + i][wid*32 + sub*16 + l15] = (_Float16)hnew;
      }
    hx[m2][128 + c2] = (_Float16)xpre;
    __syncthreads();

    { half4 hv = *(const half4*)&hx[m2][c2*4];
      *(half4*)((void*)&enc_out[((size_t)(b0 + m2)*512 + t)*128 + c2*4]) = hv; }
  }

  if (lq < 2)
    #pragma unroll
    for (int sub = 0; sub < 2; ++sub)
      #pragma unroll
      for (int i = 0; i < 4; ++i)
        hfin[(size_t)(b0 + 4*lq + i)*128 + wid*32 + sub*16 + l15] = hreg[sub][i];
}

// ================= decoder: MFMA, 1 batch/block, E in LDS =================
struct DecSmem {
  _Float16 E[512*128];    // 128 KB
  float lw[512];
  float wsm[512];
  float ctxp[8*128];
  float hsm[128];
  _Float16 hy[160];       // [h | y] fp16 (logits A)
  _Float16 cxh[256];      // [ctx | h] fp16 (GRU A)
  float red[16];
  float outp[256];
  float absm[512];
  float bRZ[256];
  float bNH[128];
  float bNI[128];
  _Float16 o1[128*32];    // out1T staged
  float o1b[32];
  float o2w[32];
  float o2b;
};

__global__ void __launch_bounds__(256, 1) dec_kernel(const float* __restrict__ xb,
    const __half* __restrict__ enc_out, const float* __restrict__ hfin,
    const __half* __restrict__ attnF, const float* __restrict__ attn_b,
    const __half* __restrict__ decF,
    const float* __restrict__ dbih, const float* __restrict__ dbhh,
    const __half* __restrict__ out1T, const float* __restrict__ out1_b,
    const float* __restrict__ out2_W, const float* __restrict__ out2_b,
    float* __restrict__ out) {
  __shared__ __align__(16) DecSmem sm;
  const int tid = threadIdx.x, lane = tid & 63, wid = tid >> 6;
  const int l15 = lane & 15, lq = lane >> 4;
  const int b = blockIdx.x;

  { const half8* src = (const half8*)(enc_out + (size_t)b*512*128);
    half8* dst = (half8*)sm.E;
    for (int i = tid; i < 8192; i += 256) dst[i] = src[i]; }
  if (tid < 128) { float hv = hfin[(size_t)b*128 + tid];
    sm.hsm[tid] = hv; sm.hy[tid] = (_Float16)hv; sm.cxh[128 + tid] = (_Float16)hv; }
  if (tid < 32) sm.hy[128 + tid] = (_Float16)xb[((size_t)b*512 + 511)*32 + tid];
  for (int i = tid; i < 512; i += 256) sm.absm[i] = attn_b[i];
  sm.bRZ[tid] = dbih[tid] + dbhh[tid];
  if (tid < 128) { sm.bNH[tid] = dbhh[256 + tid]; sm.bNI[tid] = dbih[256 + tid]; }
  { const uint4* s4 = (const uint4*)out1T; uint4* d4 = (uint4*)sm.o1;
    for (int i = tid; i < 512; i += 256) d4[i] = s4[i]; }
  if (tid < 32) { sm.o1b[tid] = out1_b[tid]; sm.o2w[tid] = out2_W[tid]; }
  if (tid == 0) sm.o2b = out2_b[0];
  __syncthreads();

  const half8 Az = {};
  const half8* aF = (const half8*)attnF + (size_t)wid*40*64;
  const half8* dF = (const half8*)decF + (size_t)wid*48*64;

  for (int tt = 0; tt < TO; ++tt) {
    // ---- logits: [1x160]@[160x512] via MFMA (row 0 valid) ----
    half8 A[5];
    #pragma unroll
    for (int kb = 0; kb < 5; ++kb)
      A[kb] = (l15 == 0) ? *(const half8*)&sm.hy[kb*32 + lq*8] : Az;
    f32x4 CL[8];
    #pragma unroll
    for (int st = 0; st < 8; ++st) CL[st] = (f32x4){0.f,0.f,0.f,0.f};
    #pragma unroll
    for (int st = 0; st < 8; ++st)
      #pragma unroll
      for (int kb = 0; kb < 5; ++kb)
        CL[st] = __builtin_amdgcn_mfma_f32_16x16x32_f16(A[kb], aF[(st*5 + kb)*64 + lane], CL[st], 0, 0, 0);
    if (lane < 16) {
      #pragma unroll
      for (int st = 0; st < 8; ++st) {
        int s = wid*128 + st*16 + lane;
        sm.lw[s] = CL[st][0] + sm.absm[s];
      }
    }
    __syncthreads();  // B1

    // ---- softmax (shuffle reduce) ----
    float v0 = sm.lw[tid], v1 = sm.lw[tid + 256];
    float mx = fmaxf(v0, v1);
    #pragma unroll
    for (int off = 1; off < 64; off <<= 1) mx = fmaxf(mx, __shfl_xor(mx, off));
    if (lane == 0) sm.red[wid] = mx;
    __syncthreads();  // B2
    float M = fmaxf(fmaxf(sm.red[0], sm.red[1]), fmaxf(sm.red[2], sm.red[3]));
    float e0 = __expf(v0 - M), e1 = __expf(v1 - M);
    float ssum = e0 + e1;
    #pragma unroll
    for (int off = 1; off < 64; off <<= 1) ssum += __shfl_xor(ssum, off);
    if (lane == 0) sm.red[8 + wid] = ssum;
    __syncthreads();  // B3
    float inv = 1.f / (sm.red[8] + sm.red[9] + sm.red[10] + sm.red[11]);
    sm.wsm[tid] = e0 * inv; sm.wsm[tid + 256] = e1 * inv;
    __syncthreads();  // B4

    // ---- ctx = w @ E (VALU over LDS) ----
    { const int hq = tid & 31, sg = tid >> 5;
      float c0 = 0.f, c1 = 0.f, c2 = 0.f, c3 = 0.f;
      #pragma unroll 8
      for (int ii = 0; ii < 64; ++ii) {
        int s = sg*64 + ii;
        float wv = sm.wsm[s];
        half4 ev = *(const half4*)&sm.E[s*128 + hq*4];
        c0 += wv * (float)ev[0]; c1 += wv * (float)ev[1];
        c2 += wv * (float)ev[2]; c3 += wv * (float)ev[3];
      }
      f32x4 cc = {c0, c1, c2, c3};
      *(f32x4*)&sm.ctxp[sg*128 + hq*4] = cc; }
    __syncthreads();  // B5
    if (tid < 128) {
      float c = 0.f;
      #pragma unroll
      for (int g = 0; g < 8; ++g) c += sm.ctxp[g*128 + tid];
      sm.cxh[tid] = (_Float16)c;
    }
    __syncthreads();  // B6

    // ---- GRU: [1x256]@[256x384] (+ split n-gate) via MFMA ----
    half8 Ag[8];
    #pragma unroll
    for (int kb = 0; kb < 8; ++kb)
      Ag[kb] = (l15 == 0) ? *(const half8*)&sm.cxh[kb*32 + lq*8] : Az;
    f32x4 Crz[4], Cnh[2], Cni[2];
    #pragma unroll
    for (int t4 = 0; t4 < 4; ++t4) Crz[t4] = (f32x4){0.f,0.f,0.f,0.f};
    #pragma unroll
    for (int sub = 0; sub < 2; ++sub) { Cnh[sub] = (f32x4){0.f,0.f,0.f,0.f}; Cni[sub] = (f32x4){0.f,0.f,0.f,0.f}; }
    #pragma unroll
    for (int t4 = 0; t4 < 4; ++t4)
      #pragma unroll
      for (int kb = 0; kb < 8; ++kb)
        Crz[t4] = __builtin_amdgcn_mfma_f32_16x16x32_f16(Ag[kb], dF[(t4*8 + kb)*64 + lane], Crz[t4], 0, 0, 0);
    #pragma unroll
    for (int sub = 0; sub < 2; ++sub)
      #pragma unroll
      for (int kb = 0; kb < 4; ++kb)
        Cnh[sub] = __builtin_amdgcn_mfma_f32_16x16x32_f16(Ag[4 + kb], dF[(32 + sub*4 + kb)*64 + lane], Cnh[sub], 0, 0, 0);
    #pragma unroll
    for (int sub = 0; sub < 2; ++sub)
      #pragma unroll
      for (int kb = 0; kb < 4; ++kb)
        Cni[sub] = __builtin_amdgcn_mfma_f32_16x16x32_f16(Ag[kb], dF[(40 + sub*4 + kb)*64 + lane], Cni[sub], 0, 0, 0);
    __syncthreads();  // B6.5: all cxh reads complete before h rewrite
    if (lane < 16) {
      #pragma unroll
      for (int sub = 0; sub < 2; ++sub) {
        int j = wid*32 + sub*16 + lane;
        float r = 1.f / (1.f + __expf(-(Crz[sub][0] + sm.bRZ[j])));
        float z = 1.f / (1.f + __expf(-(Crz[2 + sub][0] + sm.bRZ[128 + j])));
        float narg = (Cni[sub][0] + sm.bNI[j]) + r * (Cnh[sub][0] + sm.bNH[j]);
        float n = 1.f - 2.f / (__expf(2.f*narg) + 1.f);
        float hnew = (1.f - z)*n + z*sm.hsm[j];
        sm.hsm[j] = hnew;
        sm.hy[j] = (_Float16)hnew;
        sm.cxh[128 + j] = (_Float16)hnew;
      }
    }
    __syncthreads();  // B7

    // ---- out1 / out2 ----
    { int f = tid & 31, kq = tid >> 5;
      float a = 0.f;
      #pragma unroll
      for (int k2 = 0; k2 < 16; ++k2) { int k = kq*16 + k2; a += (float)sm.o1[k*32 + f] * sm.hsm[k]; }
      sm.outp[kq*32 + f] = a; }
    __syncthreads();  // B8
    if (tid < 32) {
      float o = sm.o1b[tid];
      #pragma unroll
      for (int g = 0; g < 8; ++g) o += sm.outp[g*32 + tid];
      sm.hy[128 + tid] = (_Float16)o;               // raw out feeds next attention
      float v = fmaxf(o, 0.f) * sm.o2w[tid];
      #pragma unroll
      for (int off = 1; off < 32; off <<= 1) v += __shfl_xor(v, off);
      if (tid == 0) out[(size_t)b*TO + tt] = fmaxf(v + sm.o2b, 0.f);
    }
    __syncthreads();  // B9
  }
}

extern "C" void kernel_launch(void* const* d_in, const int* in_sizes, int n_in,
                              void* d_out, int out_size, void* d_ws, size_t ws_size,
                              hipStream_t stream) {
  const float* xb      = (const float*)d_in[0];
  const float* enc_Wih = (const float*)d_in[1];
  const float* enc_Whh = (const float*)d_in[2];
  const float* enc_bih = (const float*)d_in[3];
  const float* enc_bhh = (const float*)d_in[4];
  const float* attn_W  = (const float*)d_in[5];
  const float* attn_b  = (const float*)d_in[6];
  const float* dec_Wih = (const float*)d_in[7];
  const float* dec_Whh = (const float*)d_in[8];
  const float* dec_bih = (const float*)d_in[9];
  const float* dec_bhh = (const float*)d_in[10];
  const float* out1_W  = (const float*)d_in[11];
  const float* out1_b  = (const float*)d_in[12];
  const float* out2_W  = (const float*)d_in[13];
  const float* out2_b  = (const float*)d_in[14];

  char* ws = (char*)d_ws;
  __half* enc_out = (__half*)(ws + OFF_ENCOUT);
  float*  hfin    = (float*)(ws + OFF_HFIN);
  __half* attnF   = (__half*)(ws + OFF_ATTNF);
  __half* decF    = (__half*)(ws + OFF_DECF);
  __half* out1T   = (__half*)(ws + OFF_OUT1T);
  __half* Wf      = (__half*)(ws + OFF_WF);

  prep_kernel<<<960, 256, 0, stream>>>(attn_W, dec_Wih, dec_Whh, out1_W, enc_Wih, enc_Whh,
                                       attnF, decF, out1T, Wf);
  enc_kernel<<<256, 256, 0, stream>>>(xb, Wf, enc_bih, enc_bhh, enc_out, hfin);
  dec_kernel<<<2048, 256, 0, stream>>>(xb, enc_out, hfin, attnF, attn_b, decF,
                                       dec_bih, dec_bhh, out1T, out1_b, out2_W, out2_b,
                                       (float*)d_out);
}